// Round 1
// baseline (212.867 us; speedup 1.0000x reference)
//
#include <hip/hip_runtime.h>

constexpr int IN_DIM = 128;
constexpr int OUT_DIM = 64;
constexpr int EDGE_DIM = 16;
constexpr int BS = 8;
constexpr int NN = 512;
constexpr int ROWS = BS * NN;   // 4096

// ---------------------------------------------------------------------------
// Kernel 1: h = x @ W^T  (row-major h: (ROWS, 64)), s_i = h·a_i, s_j = h·a_j
// 256 blocks x 256 threads; each wave handles 4 rows (lane = output dim o).
// x rows staged in LDS (broadcast reads), W read via float4 from L2.
// ---------------------------------------------------------------------------
__global__ __launch_bounds__(256, 2) void fc_kernel(
    const float* __restrict__ x, const float* __restrict__ W,
    const float* __restrict__ attn_w,
    float* __restrict__ h, float* __restrict__ si, float* __restrict__ sj)
{
    __shared__ float xs[16 * IN_DIM];     // 16 rows x 128 = 8 KB
    const int t    = threadIdx.x;
    const int lane = t & 63;              // output dim o
    const int w    = t >> 6;              // wave id 0..3
    const int rowBase = blockIdx.x * 16;

    // stage 16 x-rows: 2048 floats = 512 float4
    const float4* x4 = (const float4*)(x + (size_t)rowBase * IN_DIM);
    float4* xs4 = (float4*)xs;
    xs4[t]       = x4[t];
    xs4[t + 256] = x4[t + 256];

    const float a_i = attn_w[lane];
    const float a_j = attn_w[OUT_DIM + lane];
    __syncthreads();

    const float4* W4 = (const float4*)W;  // row o at W4[o*32 + k]
    float acc[4] = {0.f, 0.f, 0.f, 0.f};
    #pragma unroll 8
    for (int k = 0; k < IN_DIM / 4; ++k) {
        float4 wv = W4[lane * (IN_DIM / 4) + k];
        #pragma unroll
        for (int r = 0; r < 4; ++r) {
            float4 xv = ((const float4*)&xs[(w * 4 + r) * IN_DIM])[k];
            acc[r] += xv.x * wv.x + xv.y * wv.y + xv.z * wv.z + xv.w * wv.w;
        }
    }
    #pragma unroll
    for (int r = 0; r < 4; ++r) {
        const int row = rowBase + w * 4 + r;
        h[(size_t)row * OUT_DIM + lane] = acc[r];
        float pi = acc[r] * a_i;
        float pj = acc[r] * a_j;
        #pragma unroll
        for (int off = 32; off > 0; off >>= 1) {
            pi += __shfl_down(pi, off, 64);
            pj += __shfl_down(pj, off, 64);
        }
        if (lane == 0) { si[row] = pi; sj[row] = pj; }
    }
}

// ---------------------------------------------------------------------------
// Kernel 2: one block per (b,i). Fused: e_j = s_i + s_j[j] + edge[b,i,j,:]·a_e
// -> softmax over j (block reduce) -> out[b,i,:] = sum_j alpha_j * h[b,j,:].
// edge_feats read exactly once; alpha lives in LDS only.
// ---------------------------------------------------------------------------
__global__ __launch_bounds__(256, 4) void attn_kernel(
    const float* __restrict__ edge, const float* __restrict__ attn_w,
    const float* __restrict__ h, const float* __restrict__ si,
    const float* __restrict__ sj, float* __restrict__ out)
{
    __shared__ float alpha[NN];           // 2 KB
    __shared__ float redm[4];
    __shared__ float reds[4];
    __shared__ float4 part[16][16];       // 4 KB

    const int t    = threadIdx.x;
    const int lane = t & 63;
    const int w    = t >> 6;
    const int blk  = blockIdx.x;          // b*NN + i
    const int b    = blk >> 9;

    const float4* ae4 = (const float4*)(attn_w + 2 * OUT_DIM);
    const float4 ae0 = ae4[0], ae1 = ae4[1], ae2 = ae4[2], ae3 = ae4[3];
    const float  siv = si[blk];
    const float4* ef4 = (const float4*)edge + (size_t)blk * NN * EDGE_DIM / 4;
    const float* sjb  = sj + (b << 9);

    // ---- phase 1: e_j for j = t and j = t+256 ----
    float e0, e1;
    {
        int j = t;
        float4 v0 = ef4[j * 4 + 0], v1 = ef4[j * 4 + 1];
        float4 v2 = ef4[j * 4 + 2], v3 = ef4[j * 4 + 3];
        float se = v0.x * ae0.x + v0.y * ae0.y + v0.z * ae0.z + v0.w * ae0.w
                 + v1.x * ae1.x + v1.y * ae1.y + v1.z * ae1.z + v1.w * ae1.w
                 + v2.x * ae2.x + v2.y * ae2.y + v2.z * ae2.z + v2.w * ae2.w
                 + v3.x * ae3.x + v3.y * ae3.y + v3.z * ae3.z + v3.w * ae3.w;
        e0 = siv + sjb[j] + se;
        j = t + 256;
        v0 = ef4[j * 4 + 0]; v1 = ef4[j * 4 + 1];
        v2 = ef4[j * 4 + 2]; v3 = ef4[j * 4 + 3];
        se = v0.x * ae0.x + v0.y * ae0.y + v0.z * ae0.z + v0.w * ae0.w
           + v1.x * ae1.x + v1.y * ae1.y + v1.z * ae1.z + v1.w * ae1.w
           + v2.x * ae2.x + v2.y * ae2.y + v2.z * ae2.z + v2.w * ae2.w
           + v3.x * ae3.x + v3.y * ae3.y + v3.z * ae3.z + v3.w * ae3.w;
        e1 = siv + sjb[j] + se;
    }

    // ---- softmax max ----
    float m = fmaxf(e0, e1);
    #pragma unroll
    for (int off = 32; off > 0; off >>= 1) m = fmaxf(m, __shfl_down(m, off, 64));
    if (lane == 0) redm[w] = m;
    __syncthreads();
    m = fmaxf(fmaxf(redm[0], redm[1]), fmaxf(redm[2], redm[3]));

    // ---- softmax exp + sum ----
    const float p0 = __expf(e0 - m);
    const float p1 = __expf(e1 - m);
    alpha[t]       = p0;
    alpha[t + 256] = p1;
    float s = p0 + p1;
    #pragma unroll
    for (int off = 32; off > 0; off >>= 1) s += __shfl_down(s, off, 64);
    if (lane == 0) reds[w] = s;
    __syncthreads();                      // alpha[] + reds[] now visible
    const float rinv = 1.0f / (reds[0] + reds[1] + reds[2] + reds[3]);

    // ---- phase 3: out[b,i,:] = rinv * sum_j alpha[j] * h[b,j,:] ----
    const int o4 = t & 15;                // float4 chunk of the 64-dim output
    const int g  = t >> 4;                // 16 groups over j
    const float4* h4 = (const float4*)(h + ((size_t)(b << 9)) * OUT_DIM);
    float4 acc = {0.f, 0.f, 0.f, 0.f};
    #pragma unroll 4
    for (int j = g; j < NN; j += 16) {
        const float a  = alpha[j];
        const float4 hv = h4[j * 16 + o4];
        acc.x += a * hv.x; acc.y += a * hv.y;
        acc.z += a * hv.z; acc.w += a * hv.w;
    }
    part[g][o4] = acc;
    __syncthreads();
    if (t < 16) {
        float4 r = part[0][t];
        #pragma unroll
        for (int g2 = 1; g2 < 16; ++g2) {
            const float4 p = part[g2][t];
            r.x += p.x; r.y += p.y; r.z += p.z; r.w += p.w;
        }
        r.x *= rinv; r.y *= rinv; r.z *= rinv; r.w *= rinv;
        ((float4*)out)[(size_t)blk * 16 + t] = r;
    }
}

extern "C" void kernel_launch(void* const* d_in, const int* in_sizes, int n_in,
                              void* d_out, int out_size, void* d_ws, size_t ws_size,
                              hipStream_t stream) {
    const float* x      = (const float*)d_in[0];
    const float* edge   = (const float*)d_in[1];
    const float* W_fc   = (const float*)d_in[2];
    const float* attn_w = (const float*)d_in[3];
    float* out = (float*)d_out;

    float* h  = (float*)d_ws;             // ROWS*64 floats = 1 MiB
    float* si = h + (size_t)ROWS * OUT_DIM;
    float* sj = si + ROWS;

    fc_kernel<<<ROWS / 16, 256, 0, stream>>>(x, W_fc, attn_w, h, si, sj);
    attn_kernel<<<ROWS, 256, 0, stream>>>(edge, attn_w, h, si, sj, out);
}

// Round 2
// 210.293 us; speedup vs baseline: 1.0122x; 1.0122x over previous
//
#include <hip/hip_runtime.h>

constexpr int IN_DIM = 128;
constexpr int OUT_DIM = 64;
constexpr int EDGE_DIM = 16;
constexpr int BS = 8;
constexpr int NN = 512;
constexpr int ROWS = BS * NN;   // 4096
constexpr int TI = 4;           // attention rows per block

// ---------------------------------------------------------------------------
// Kernel 1: h = x @ W^T (row-major h: (ROWS,64)), s_i = h·a_i, s_j = h·a_j
// 512 blocks x 256 threads; each wave handles 2 rows (lane = output dim o).
// ---------------------------------------------------------------------------
__global__ __launch_bounds__(256, 4) void fc_kernel(
    const float* __restrict__ x, const float* __restrict__ W,
    const float* __restrict__ attn_w,
    float* __restrict__ h, float* __restrict__ si, float* __restrict__ sj)
{
    __shared__ float xs[8 * IN_DIM];      // 8 rows x 128 = 4 KB
    const int t    = threadIdx.x;
    const int lane = t & 63;              // output dim o
    const int w    = t >> 6;              // wave id 0..3
    const int rowBase = blockIdx.x * 8;

    // stage 8 x-rows: 1024 floats = 256 float4 (one per thread)
    ((float4*)xs)[t] = ((const float4*)(x + (size_t)rowBase * IN_DIM))[t];

    const float a_i = attn_w[lane];
    const float a_j = attn_w[OUT_DIM + lane];
    __syncthreads();

    const float4* W4 = (const float4*)W;  // row o at W4[o*32 + k]
    float acc0 = 0.f, acc1 = 0.f;
    const float4* xr0 = (const float4*)&xs[(w * 2 + 0) * IN_DIM];
    const float4* xr1 = (const float4*)&xs[(w * 2 + 1) * IN_DIM];
    #pragma unroll 8
    for (int k = 0; k < IN_DIM / 4; ++k) {
        const float4 wv = W4[lane * (IN_DIM / 4) + k];
        const float4 x0 = xr0[k];
        const float4 x1 = xr1[k];
        acc0 += x0.x * wv.x + x0.y * wv.y + x0.z * wv.z + x0.w * wv.w;
        acc1 += x1.x * wv.x + x1.y * wv.y + x1.z * wv.z + x1.w * wv.w;
    }
    #pragma unroll
    for (int r = 0; r < 2; ++r) {
        const float a   = r ? acc1 : acc0;
        const int   row = rowBase + w * 2 + r;
        h[(size_t)row * OUT_DIM + lane] = a;
        float pi = a * a_i;
        float pj = a * a_j;
        #pragma unroll
        for (int m = 32; m > 0; m >>= 1) {
            pi += __shfl_xor(pi, m, 64);
            pj += __shfl_xor(pj, m, 64);
        }
        if (lane == 0) { si[row] = pi; sj[row] = pj; }
    }
}

// ---------------------------------------------------------------------------
// Kernel 2: TI=4 rows i per block; wave w owns row i_base+w.
// Per wave: e_j = s_i + s_j[j] + edge[b,i,j,:]·a_e for 8 j's per lane,
// softmax entirely via __shfl_xor (no barriers), normalized alpha -> LDS.
// One barrier, then block-wide alpha(4x512) x h(512x64): h read ONCE/block.
// ---------------------------------------------------------------------------
__global__ __launch_bounds__(256, 4) void attn_kernel(
    const float* __restrict__ edge, const float* __restrict__ attn_w,
    const float* __restrict__ h, const float* __restrict__ si,
    const float* __restrict__ sj, float* __restrict__ out)
{
    __shared__ float  alpha[TI * NN];     // 8 KB (normalized alpha)
    __shared__ float4 part[TI][16][16];   // 16 KB

    const int t    = threadIdx.x;
    const int lane = t & 63;
    const int w    = t >> 6;              // wave = local row r
    const int blk  = blockIdx.x;          // b*128 + itile
    const int b    = blk >> 7;
    const int iRow = (blk & 127) * TI + w;        // i within batch
    const int rowg = (b << 9) + iRow;             // global row

    const float4* ae4 = (const float4*)(attn_w + 2 * OUT_DIM);
    const float4 ae0 = ae4[0], ae1 = ae4[1], ae2 = ae4[2], ae3 = ae4[3];
    const float  siv = si[rowg];
    const float4* ef4 = (const float4*)edge + (size_t)rowg * NN * EDGE_DIM / 4;
    const float* sjb  = sj + (b << 9);

    // ---- phase 1: e_j for j = jj*64 + lane, jj = 0..7 ----
    float e[8];
    #pragma unroll 2
    for (int jj = 0; jj < 8; ++jj) {
        const int j = jj * 64 + lane;
        const float4 v0 = ef4[j * 4 + 0], v1 = ef4[j * 4 + 1];
        const float4 v2 = ef4[j * 4 + 2], v3 = ef4[j * 4 + 3];
        const float se = v0.x * ae0.x + v0.y * ae0.y + v0.z * ae0.z + v0.w * ae0.w
                       + v1.x * ae1.x + v1.y * ae1.y + v1.z * ae1.z + v1.w * ae1.w
                       + v2.x * ae2.x + v2.y * ae2.y + v2.z * ae2.z + v2.w * ae2.w
                       + v3.x * ae3.x + v3.y * ae3.y + v3.z * ae3.z + v3.w * ae3.w;
        e[jj] = siv + sjb[j] + se;
    }

    // ---- wave-local softmax (row per wave, no barriers) ----
    float m = e[0];
    #pragma unroll
    for (int jj = 1; jj < 8; ++jj) m = fmaxf(m, e[jj]);
    #pragma unroll
    for (int msk = 32; msk > 0; msk >>= 1) m = fmaxf(m, __shfl_xor(m, msk, 64));

    float p[8], s = 0.f;
    #pragma unroll
    for (int jj = 0; jj < 8; ++jj) { p[jj] = __expf(e[jj] - m); s += p[jj]; }
    #pragma unroll
    for (int msk = 32; msk > 0; msk >>= 1) s += __shfl_xor(s, msk, 64);
    const float rinv = 1.0f / s;
    #pragma unroll
    for (int jj = 0; jj < 8; ++jj)
        alpha[w * NN + jj * 64 + lane] = p[jj] * rinv;

    __syncthreads();

    // ---- phase 3: out[r,:] = sum_j alpha[r][j] * h[b,j,:], h read once ----
    const int o4 = t & 15;                // float4 chunk of 64-dim output
    const int g  = t >> 4;                // 16 groups over j
    const float4* h4 = (const float4*)(h + ((size_t)(b << 9)) * OUT_DIM);
    float4 acc[TI];
    #pragma unroll
    for (int r = 0; r < TI; ++r) acc[r] = make_float4(0.f, 0.f, 0.f, 0.f);
    #pragma unroll 4
    for (int j = g; j < NN; j += 16) {
        const float4 hv = h4[j * 16 + o4];
        #pragma unroll
        for (int r = 0; r < TI; ++r) {
            const float a = alpha[r * NN + j];   // 16-lane broadcast
            acc[r].x += a * hv.x; acc[r].y += a * hv.y;
            acc[r].z += a * hv.z; acc[r].w += a * hv.w;
        }
    }
    #pragma unroll
    for (int r = 0; r < TI; ++r) part[r][g][o4] = acc[r];
    __syncthreads();

    if (t < 64) {
        const int r = t >> 4, c = t & 15;
        float4 v = part[r][0][c];
        #pragma unroll
        for (int g2 = 1; g2 < 16; ++g2) {
            const float4 q = part[r][g2][c];
            v.x += q.x; v.y += q.y; v.z += q.z; v.w += q.w;
        }
        ((float4*)out)[((size_t)(b << 9) + (blk & 127) * TI + r) * 16 + c] = v;
    }
}

extern "C" void kernel_launch(void* const* d_in, const int* in_sizes, int n_in,
                              void* d_out, int out_size, void* d_ws, size_t ws_size,
                              hipStream_t stream) {
    const float* x      = (const float*)d_in[0];
    const float* edge   = (const float*)d_in[1];
    const float* W_fc   = (const float*)d_in[2];
    const float* attn_w = (const float*)d_in[3];
    float* out = (float*)d_out;

    float* h  = (float*)d_ws;             // ROWS*64 floats = 1 MiB
    float* si = h + (size_t)ROWS * OUT_DIM;
    float* sj = si + ROWS;

    fc_kernel<<<ROWS / 8, 256, 0, stream>>>(x, W_fc, attn_w, h, si, sj);
    attn_kernel<<<ROWS / TI, 256, 0, stream>>>(edge, attn_w, h, si, sj, out);
}